// Round 3
// baseline (267.850 us; speedup 1.0000x reference)
//
#include <hip/hip_runtime.h>
#include <hip/hip_bf16.h>

typedef __attribute__((ext_vector_type(8))) short short8;
typedef __attribute__((ext_vector_type(4))) float f32x4;

#define B_ 8
#define C_ 64
#define H_ 256
#define W_ 256
#define HW_ 65536
#define K_ 10
#define NS1 24
#define NS2 18
#define WSTRIDE 68   // slab w-stride (rows of 128B)

static __device__ __forceinline__ unsigned short f2bf(float f) {
    __hip_bfloat16 hb = __float2bfloat16(f);
    return *(unsigned short*)&hb;
}
static __device__ __forceinline__ float bf2f(unsigned short u) {
    unsigned v = ((unsigned)u) << 16;
    float f;
    __builtin_memcpy(&f, &v, 4);
    return f;
}

// ---------------------------------------------------------------------------
// Fragment-ordered, gamma-folded, expert-mixed weights + biases.
// W4_1: [b][24 steps][4 ofrag][64 lane][8] bf16 (0..17 conv taps, 18..23 1x1)
// W4_2: [b][18 steps][4][64][8] bf16
// ---------------------------------------------------------------------------
__global__ void k_combine(const float* __restrict__ attn, const float* __restrict__ gamma,
                          const float* __restrict__ w1, const float* __restrict__ b1,
                          const float* __restrict__ w2, const float* __restrict__ b2,
                          const float* __restrict__ w16, const float* __restrict__ w168,
                          const float* __restrict__ w88,
                          unsigned short* __restrict__ W4_1, unsigned short* __restrict__ W4_2,
                          float* __restrict__ bias1, float* __restrict__ bias2) {
    const int N1 = B_ * NS1 * 2048;
    const int N2 = B_ * NS2 * 2048;
    int gid = blockIdx.x * 256 + threadIdx.x;
    if (gid < N1) {
        int b = gid / (NS1 * 2048);
        int r = gid - b * (NS1 * 2048);
        int s = r >> 11;
        int r2 = r & 2047;
        int of = r2 >> 9, l = (r2 >> 3) & 63, j = r2 & 7;
        int o = of * 16 + (l & 15);
        int g = l >> 4;
        float val;
        if (s < 18) {
            int t = s >> 1, h = s & 1;
            int c = h * 32 + g * 8 + j;
            float acc = 0.f;
            #pragma unroll
            for (int k = 0; k < K_; ++k)
                acc += attn[b * K_ + k] * w2[((size_t)(k * 64 + o) * 64 + c) * 9 + t];
            val = acc * gamma[b * 64 + o];
        } else {
            int e = s - 18;
            int m = e >> 1, h = e & 1;
            int c = h * 32 + g * 8 + j;
            const float* wm = (m == 0) ? w16 : (m == 1 ? w168 : w88);
            val = wm[o * 64 + c];
        }
        W4_1[gid] = f2bf(val);
    } else if (gid < N1 + N2) {
        int gid2 = gid - N1;
        int b = gid2 / (NS2 * 2048);
        int r = gid2 - b * (NS2 * 2048);
        int s = r >> 11;
        int r2 = r & 2047;
        int of = r2 >> 9, l = (r2 >> 3) & 63, j = r2 & 7;
        int o = of * 16 + (l & 15);
        int g = l >> 4;
        int t = s >> 1, h = s & 1;
        int c = h * 32 + g * 8 + j;
        float acc = 0.f;
        #pragma unroll
        for (int k = 0; k < K_; ++k)
            acc += attn[b * K_ + k] * w1[((size_t)(k * 64 + o) * 64 + c) * 9 + t];
        W4_2[gid2] = f2bf(acc * gamma[b * 64 + o]);
    } else if (gid < N1 + N2 + 1024) {
        int id2 = gid - N1 - N2;
        int b = id2 >> 7;
        int rest = id2 & 127;
        int o = rest >> 1;
        int which = rest & 1;
        const float* bb = which ? b1 : b2;
        float acc = 0.f;
        #pragma unroll
        for (int k = 0; k < K_; ++k) acc += attn[b * K_ + k] * bb[k * 64 + o];
        float v = acc * gamma[b * 64 + o];
        if (which) bias2[b * 64 + o] = v; else bias1[b * 64 + o] = v;
    }
}

// ---------------------------------------------------------------------------
// x [b][64][HW] f32  ->  X1 [b][HW][64] bf16
// ---------------------------------------------------------------------------
__global__ __launch_bounds__(256) void k_prep(const float* __restrict__ x,
                                              unsigned short* __restrict__ X1) {
    __shared__ float ls[64][65];
    const int b = blockIdx.y;
    const int px0 = blockIdx.x * 64;
    const int t = threadIdx.x;
    for (int e = t; e < 4096; e += 256) {
        int ch = e >> 6, px = e & 63;
        ls[ch][px] = x[((size_t)b * 64 + ch) * HW_ + px0 + px];
    }
    __syncthreads();
    for (int e = t; e < 4096; e += 256) {
        int ch = e & 63, px = e >> 6;
        X1[((size_t)b * HW_ + px0 + px) * 64 + ch] = f2bf(ls[ch][px]);
    }
}

// ---- helpers (inline; all call sites fully unrolled so s is compile-time)
static __device__ __forceinline__ void load_b4(const unsigned short* __restrict__ Wb,
                                               int l, int s, short8* d) {
    const unsigned short* wp = Wb + s * 2048 + l * 8;
    d[0] = *(const short8*)(wp);
    d[1] = *(const short8*)(wp + 512);
    d[2] = *(const short8*)(wp + 1024);
    d[3] = *(const short8*)(wp + 1536);
}
static __device__ __forceinline__ void load_a4(const short* xs, int wv, int ln15, int g,
                                               int s, short8* d) {
    const int t = s >> 1, h = s & 1;
    const int dh = t / 3, dw = t - 3 * dh;
    #pragma unroll
    for (int mf = 0; mf < 4; ++mf) {
        int wr = 16 * mf + ln15 + dw;
        d[mf] = *(const short8*)((const char*)xs +
                 ((wv + dh) * WSTRIDE + wr) * 128 + ((((h << 2) | g) ^ (wr & 7)) * 16));
    }
}

// ---------------------------------------------------------------------------
// Implicit-GEMM conv3x3 via MFMA. Tile: 4 img-rows x 64 w x 64 o, 4 waves.
// Software-pipelined (depth-1 prefetch of B-global and A-LDS fragments).
// ---------------------------------------------------------------------------
template<int STAGE>
__global__ __launch_bounds__(256) void k_conv(
    const unsigned short* __restrict__ Xin,   // [b][px][64] bf16
    const float* __restrict__ x_res,          // stage2 residual [b][o][px]
    const float* __restrict__ par,            // stage1 [b][3][HW]
    const unsigned short* __restrict__ W4,    // [b][NS][4][64][8] bf16
    const float* __restrict__ bias,           // [b][64]
    unsigned short* __restrict__ Tout,        // stage1 out [b][px][64] bf16
    float* __restrict__ Fout)                 // stage2 out [b][64][HW] f32
{
    __shared__ short xs[6 * WSTRIDE * 64];    // 52224 B

    const int tid = threadIdx.x;
    const int l = tid & 63;
    const int wv = tid >> 6;
    const int b = blockIdx.y;
    const int rblk = blockIdx.x >> 2;         // 0..63
    const int cblk = blockIdx.x & 3;          // 0..3
    const int gh0 = rblk * 4, w0 = cblk * 64;
    const int ln15 = l & 15, g = l >> 4;

    const unsigned short* Xb = Xin + (size_t)b * HW_ * 64;
    const unsigned short* Wb = W4 + (size_t)b * ((STAGE == 1 ? NS1 : NS2) * 2048);

    f32x4 acc[4][4];
    #pragma unroll
    for (int mf = 0; mf < 4; ++mf)
        #pragma unroll
        for (int of = 0; of < 4; ++of)
            acc[mf][of] = (f32x4){0.f, 0.f, 0.f, 0.f};

    // ---- stage slab: [6 rows][66 of 68 w][64 ch], zero-padded at image edges
    #pragma unroll 1
    for (int it = 0; it < 13; ++it) {
        int tau = tid + it * 256;
        if (tau < 6 * 66 * 8) {
            int slot = tau & 7;
            int rest = tau >> 3;
            int w = rest % 66;
            int rr = rest / 66;
            int gh = gh0 + rr - 1, gw = w0 + w - 1;
            short8 v = {0, 0, 0, 0, 0, 0, 0, 0};
            if ((unsigned)gh < H_ && (unsigned)gw < W_) {
                int cb = slot ^ (w & 7);
                v = *(const short8*)(Xb + ((size_t)(gh * W_ + gw)) * 64 + cb * 8);
            }
            *(short8*)((char*)xs + (rr * WSTRIDE + w) * 128 + slot * 16) = v;
        }
    }

    short8 bb[2][4], aa[2][4];
    load_b4(Wb, l, 0, bb[0]);      // B doesn't depend on LDS: issue before barrier
    __syncthreads();
    load_a4(xs, wv, ln15, g, 0, aa[0]);

    // ---- 9 taps x 2 K-halves, depth-1 pipelined
    #pragma unroll
    for (int s = 0; s < 18; ++s) {
        if (s < 17) {
            load_b4(Wb, l, s + 1, bb[(s + 1) & 1]);
            load_a4(xs, wv, ln15, g, s + 1, aa[(s + 1) & 1]);
        }
        #pragma unroll
        for (int mf = 0; mf < 4; ++mf) {
            #pragma unroll
            for (int of = 0; of < 4; ++of)
                acc[mf][of] = __builtin_amdgcn_mfma_f32_16x16x32_bf16(
                    aa[s & 1][mf], bb[s & 1][of], acc[mf][of], 0, 0, 0);
        }
    }

    if constexpr (STAGE == 1) {
        // ---- pull center 4x64 px from slab into regs; per-m scale in place
        short8 xreg[8];
        float pv[3][8];
        #pragma unroll
        for (int it = 0; it < 8; ++it) {
            int tau = tid + it * 256;
            int slot = tau & 7;
            int rest = tau >> 3;
            int wc = (rest & 63) + 1;
            int rc = (rest >> 6) + 1;
            xreg[it] = *(const short8*)((const char*)xs + (rc * WSTRIDE + wc) * 128 + slot * 16);
            int px = (gh0 + rc - 1) * W_ + (w0 + wc - 1);
            pv[0][it] = par[((size_t)b * 3 + 0) * HW_ + px];
            pv[1][it] = par[((size_t)b * 3 + 1) * HW_ + px];
            pv[2][it] = par[((size_t)b * 3 + 2) * HW_ + px];
        }
        __syncthreads();   // all center reads done before overwrite
        #pragma unroll
        for (int m = 0; m < 3; ++m) {
            short8 pb[2][4];
            load_b4(Wb, l, 18 + 2 * m, pb[0]);
            load_b4(Wb, l, 19 + 2 * m, pb[1]);
            #pragma unroll
            for (int it = 0; it < 8; ++it) {
                int tau = tid + it * 256;
                int slot = tau & 7;
                int rest = tau >> 3;
                int wc = (rest & 63) + 1;
                int rc = (rest >> 6) + 1;
                short8 o8;
                #pragma unroll
                for (int q = 0; q < 8; ++q)
                    o8[q] = (short)f2bf(bf2f((unsigned short)xreg[it][q]) * pv[m][it]);
                *(short8*)((char*)xs + (rc * WSTRIDE + wc) * 128 + slot * 16) = o8;
            }
            __syncthreads();
            short8 pa[2][4];
            load_a4(xs, wv, ln15, g, 8, pa[0]);   // s=8 -> dh=1,dw=1,h=0
            load_a4(xs, wv, ln15, g, 9, pa[1]);   // s=9 -> dh=1,dw=1,h=1
            #pragma unroll
            for (int h = 0; h < 2; ++h)
                #pragma unroll
                for (int mf = 0; mf < 4; ++mf)
                    #pragma unroll
                    for (int of = 0; of < 4; ++of)
                        acc[mf][of] = __builtin_amdgcn_mfma_f32_16x16x32_bf16(
                            pa[h][mf], pb[h][of], acc[mf][of], 0, 0, 0);
            if (m < 2) __syncthreads();
        }
    }

    // ---- epilogue
    const int gh = gh0 + wv;
    if constexpr (STAGE == 1) {
        #pragma unroll
        for (int of = 0; of < 4; ++of) {
            int o = of * 16 + ln15;
            float bi = bias[b * 64 + o];
            #pragma unroll
            for (int mf = 0; mf < 4; ++mf) {
                #pragma unroll
                for (int q = 0; q < 4; ++q) {
                    int gw = w0 + 16 * mf + g * 4 + q;
                    float v = acc[mf][of][q] + bi;
                    v = fmaxf(v, 0.f);
                    Tout[((size_t)b * HW_ + gh * W_ + gw) * 64 + o] = f2bf(v);
                }
            }
        }
    } else {
        #pragma unroll
        for (int of = 0; of < 4; ++of) {
            int o = of * 16 + ln15;
            float bi = bias[b * 64 + o];
            #pragma unroll
            for (int mf = 0; mf < 4; ++mf) {
                int gw = w0 + 16 * mf + g * 4;
                size_t idx = ((size_t)b * 64 + o) * HW_ + gh * W_ + gw;
                f32x4 xv = *(const f32x4*)(x_res + idx);
                f32x4 ov;
                #pragma unroll
                for (int q = 0; q < 4; ++q) ov[q] = xv[q] + acc[mf][of][q] + bi;
                *(f32x4*)(Fout + idx) = ov;
            }
        }
    }
}

extern "C" void kernel_launch(void* const* d_in, const int* in_sizes, int n_in,
                              void* d_out, int out_size, void* d_ws, size_t ws_size,
                              hipStream_t stream) {
    const float* x     = (const float*)d_in[0];
    const float* attn  = (const float*)d_in[1];
    const float* gamma = (const float*)d_in[2];
    const float* par   = (const float*)d_in[3];
    const float* w1    = (const float*)d_in[4];
    const float* b1    = (const float*)d_in[5];
    const float* w2    = (const float*)d_in[6];
    const float* b2    = (const float*)d_in[7];
    const float* w16   = (const float*)d_in[8];
    const float* w168  = (const float*)d_in[9];
    const float* w88   = (const float*)d_in[10];
    float* out = (float*)d_out;

    char* w = (char*)d_ws;
    unsigned short* W4_1 = (unsigned short*)w;                       // 786432 B
    unsigned short* W4_2 = (unsigned short*)(w + 786432);            // 589824 B
    float* bias1 = (float*)(w + 786432 + 589824);                    // 2048 B
    float* bias2 = (float*)(w + 786432 + 589824 + 2048);             // 2048 B
    unsigned short* X1 = (unsigned short*)(w + 1380352);             // 67108864 B
    unsigned short* T  = (unsigned short*)(w + 1380352 + 67108864);  // 67108864 B

    k_combine<<<dim3(2692), dim3(256), 0, stream>>>(attn, gamma, w1, b1, w2, b2,
                                                    w16, w168, w88, W4_1, W4_2, bias1, bias2);
    k_prep<<<dim3(1024, 8), dim3(256), 0, stream>>>(x, X1);

    dim3 grid(256, 8);
    k_conv<1><<<grid, dim3(256), 0, stream>>>(X1, nullptr, par, W4_1, bias1, T, nullptr);
    k_conv<2><<<grid, dim3(256), 0, stream>>>(T, x, nullptr, W4_2, bias2, nullptr, out);
}